// Round 2
// baseline (194.173 us; speedup 1.0000x reference)
//
#include <hip/hip_runtime.h>

#define B_   8
#define D_   256
#define HW_  16384
#define NC_  48     // NCLS*K
#define KO_  128    // key channels
#define PT_  32     // pixels per tile

using bf16x8 = __attribute__((ext_vector_type(8))) short;
using f32x4  = __attribute__((ext_vector_type(4))) float;
typedef unsigned long long ull;

__device__ __forceinline__ unsigned short f2bf(float f) {
  unsigned int u = __float_as_uint(f);
  u += 0x7FFFu + ((u >> 16) & 1u);   // RNE
  return (unsigned short)(u >> 16);
}
__device__ __forceinline__ ull pack4bf(float4 v) {
  return (ull)f2bf(v.x) | ((ull)f2bf(v.y) << 16)
       | ((ull)f2bf(v.z) << 32) | ((ull)f2bf(v.w) << 48);
}

// ---------------- P1: q = Wq.protos + bq ; Wk->bf16 ; map init ----------------
__global__ void p1_kernel(const float* __restrict__ protos,
                          const float* __restrict__ Wq,
                          const float* __restrict__ bq,
                          const float* __restrict__ Wk,
                          unsigned short* __restrict__ wk_bf,
                          unsigned short* __restrict__ q_bf,
                          float* __restrict__ protos_out,
                          short* __restrict__ map) {
  const int c = blockIdx.x;   // 0..47
  const int b = blockIdx.y;   // 0..7
  const int o = threadIdx.x;  // 0..127
  const int i = c >> 3, j = c & 7;
  const float* wq = Wq + ((size_t)i * KO_ + o) * D_;
  const float* pp = protos + (((size_t)b * 6 + i) * 8 + j) * D_;
  float acc = bq[i * KO_ + o];
  for (int d = 0; d < D_; d += 4) {
    float4 wv = *(const float4*)(wq + d);
    float4 pv = *(const float4*)(pp + d);
    acc += wv.x * pv.x + wv.y * pv.y + wv.z * pv.z + wv.w * pv.w;
  }
  q_bf[((size_t)b * NC_ + c) * KO_ + o] = f2bf(acc);
  protos_out[((size_t)c * B_ + b) * KO_ + o] = acc;
  const int gid = (b * NC_ + c) * KO_ + o;       // 0..49151
  if (gid < KO_ * D_) wk_bf[gid] = f2bf(Wk[gid]);
  for (int idx = gid; idx < B_ * HW_; idx += NC_ * B_ * KO_) map[idx] = (short)-1;
}

// ---------------- P2: nearest prototype per sampled pixel -> map ----------------
__global__ void p2_kernel(const float* __restrict__ feats,
                          const float* __restrict__ protos,
                          const int* __restrict__ xc,
                          const int* __restrict__ yc,
                          short* __restrict__ map) {
  const int sp = blockIdx.x;
  const int b  = blockIdx.y;
  const int lane = threadIdx.x;  // 0..63
  __shared__ float sel[D_];
  const int pix = xc[sp] * 128 + yc[sp];
  const float* fb = feats + (size_t)b * D_ * HW_ + pix;
  for (int k = 0; k < 4; ++k) {
    int d = lane + k * 64;
    sel[d] = fb[(size_t)d * HW_];
  }
  __syncthreads();
  float d2 = 3.4e38f;
  int bi = lane;
  if (lane < NC_) {
    const float* pf = protos + ((size_t)b * NC_ + lane) * D_;
    float nrm = 0.f, dot = 0.f;
    for (int d = 0; d < D_; d += 4) {
      float4 pv = *(const float4*)(pf + d);
      float4 sv = *(const float4*)(sel + d);
      nrm += pv.x * pv.x + pv.y * pv.y + pv.z * pv.z + pv.w * pv.w;
      dot += pv.x * sv.x + pv.y * sv.y + pv.z * sv.z + pv.w * sv.w;
    }
    d2 = nrm - 2.f * dot;
  }
  for (int off = 32; off > 0; off >>= 1) {
    float ov = __shfl_down(d2, off);
    int   oi = __shfl_down(bi, off);
    if (ov < d2 || (ov == d2 && oi < bi)) { d2 = ov; bi = oi; }
  }
  if (lane == 0) map[(size_t)b * HW_ + pix] = (short)bi;
}

// ---------------- M: fused replace + key GEMM + sim GEMM + softmax + outputs ----------------
// 128 threads (2 waves), 32 pixels/block.
// LDS: Fb bf16 [32 p][256 d] rows 512B XOR ^((p&7)<<4)  (16KB)
//      keyT bf16 [32 p][128 o] rows 256B XOR ^((p&7)<<4) (8KB)
__global__ __launch_bounds__(128, 3) void m_kernel(
    const float* __restrict__ feats, const float* __restrict__ protos,
    const unsigned short* __restrict__ wk_bf, const float* __restrict__ bk,
    const unsigned short* __restrict__ q_bf, const short* __restrict__ map,
    float* __restrict__ out_assp, float* __restrict__ out_wmax,
    float* __restrict__ out_sim, float* __restrict__ out_wmean) {
  __shared__ __align__(16) unsigned char Fb[PT_ * 512];
  __shared__ __align__(16) unsigned char keyT[PT_ * 256];
  __shared__ float wm[PT_];
  __shared__ short map_s[PT_];

  const int tid  = threadIdx.x;   // 0..127
  const int lane = tid & 63;
  const int wid  = tid >> 6;      // 0..1
  const int g    = lane >> 4;     // 0..3
  const int lr   = lane & 15;
  const int b    = blockIdx.y;
  const int p0   = blockIdx.x * PT_;
  const int p    = wid * 16 + lr; // pixel column within tile

  if (tid < PT_) map_s[tid] = map[(size_t)b * HW_ + p0 + tid];

  // ---- stage F tile: f32 global -> bf16 LDS [p][d] ----
  const int trd = tid >> 3;    // 0..15 (d sub-row)
  const int tcd = tid & 7;     // 0..7  (pixel quad)
  const float* fb = feats + (size_t)b * D_ * HW_ + p0;
  {
    const int pb = tcd * 4;
    unsigned char* r0 = Fb + (pb + 0) * 512;
    unsigned char* r1 = Fb + (pb + 1) * 512;
    unsigned char* r2 = Fb + (pb + 2) * 512;
    unsigned char* r3 = Fb + (pb + 3) * 512;
    const int x0 = ((pb + 0) & 7) << 4, x1 = ((pb + 1) & 7) << 4;
    const int x2 = ((pb + 2) & 7) << 4, x3 = ((pb + 3) & 7) << 4;
    #pragma unroll
    for (int it = 0; it < 16; ++it) {
      int d = it * 16 + trd;
      float4 v = *(const float4*)(fb + (size_t)d * HW_ + tcd * 4);
      int db = d * 2;
      *(unsigned short*)(r0 + (db ^ x0)) = f2bf(v.x);
      *(unsigned short*)(r1 + (db ^ x1)) = f2bf(v.y);
      *(unsigned short*)(r2 + (db ^ x2)) = f2bf(v.z);
      *(unsigned short*)(r3 + (db ^ x3)) = f2bf(v.w);
    }
  }
  __syncthreads();

  // ---- replace sampled pixels with nearest prototype (wave-parallel) ----
  {
    int cnt = 0;
    for (int pp = 0; pp < PT_; ++pp) {
      int c = map_s[pp];
      if (c < 0) continue;
      if ((cnt & 1) == wid) {
        float4 pv = *(const float4*)(protos + ((size_t)b * NC_ + c) * D_ + lane * 4);
        *(ull*)(Fb + pp * 512 + ((lane * 8) ^ ((pp & 7) << 4))) = pack4bf(pv);
      }
      ++cnt;
    }
  }
  __syncthreads();

  // ---- key GEMM: key[o][p] = Wk(128x256) x F(256x32), bf16 MFMA ----
  f32x4 kacc[8] = {};
  #pragma unroll
  for (int ks = 0; ks < 8; ++ks) {
    bf16x8 bfrag = *(const bf16x8*)(Fb + p * 512 + ((ks * 64 + g * 16) ^ ((p & 7) << 4)));
    #pragma unroll
    for (int ot = 0; ot < 8; ++ot) {
      bf16x8 afrag = *(const bf16x8*)(wk_bf + (size_t)(ot * 16 + lr) * D_ + ks * 32 + g * 8);
      kacc[ot] = __builtin_amdgcn_mfma_f32_16x16x32_bf16(afrag, bfrag, kacc[ot], 0, 0, 0);
    }
  }

  // ---- bias + write key^T to LDS bf16, row = p (256B), XOR ^((p&7)<<4) ----
  #pragma unroll
  for (int ot = 0; ot < 8; ++ot) {
    float4 bkv = *(const float4*)(bk + ot * 16 + g * 4);
    ull pk = (ull)f2bf(kacc[ot][0] + bkv.x)
           | ((ull)f2bf(kacc[ot][1] + bkv.y) << 16)
           | ((ull)f2bf(kacc[ot][2] + bkv.z) << 32)
           | ((ull)f2bf(kacc[ot][3] + bkv.w) << 48);
    int o0 = ot * 16 + g * 4;
    *(ull*)(keyT + p * 256 + ((o0 * 2) ^ ((p & 7) << 4))) = pk;
  }
  // keyT rows are wave-local: no barrier needed (lgkmcnt ordering within wave)

  // ---- sim GEMM: sim[c][p] = q(48x128) x key(128x32) ----
  f32x4 sacc[3] = {};
  #pragma unroll
  for (int ks = 0; ks < 4; ++ks) {
    int o0 = ks * 32 + g * 8;
    bf16x8 bfrag = *(const bf16x8*)(keyT + p * 256 + ((o0 * 2) ^ ((p & 7) << 4)));
    #pragma unroll
    for (int ct = 0; ct < 3; ++ct) {
      bf16x8 afrag = *(const bf16x8*)(q_bf + ((size_t)b * NC_ + ct * 16 + lr) * KO_ + o0);
      sacc[ct] = __builtin_amdgcn_mfma_f32_16x16x32_bf16(afrag, bfrag, sacc[ct], 0, 0, 0);
    }
  }

  // ---- softmax over c (4 lanes share a pixel: xor 16, 32) ----
  float m = -3.4e38f;
  #pragma unroll
  for (int ct = 0; ct < 3; ++ct)
    #pragma unroll
    for (int r = 0; r < 4; ++r) m = fmaxf(m, sacc[ct][r]);
  m = fmaxf(m, __shfl_xor(m, 16));
  m = fmaxf(m, __shfl_xor(m, 32));
  const float sc = 1.0f / 6.0f;   // K/C = 8/48
  float s = 0.f;
  #pragma unroll
  for (int ct = 0; ct < 3; ++ct)
    #pragma unroll
    for (int r = 0; r < 4; ++r) s += __expf((sacc[ct][r] - m) * sc);
  s += __shfl_xor(s, 16);
  s += __shfl_xor(s, 32);
  const float wmax = 1.f / s;

  // ---- write sim ----
  const size_t pixg = (size_t)p0 + p;
  #pragma unroll
  for (int ct = 0; ct < 3; ++ct)
    #pragma unroll
    for (int r = 0; r < 4; ++r) {
      int c = ct * 16 + g * 4 + r;
      out_sim[((size_t)b * NC_ + c) * HW_ + pixg] = sacc[ct][r];
    }

  if (g == 0) {
    wm[p] = wmax;
    out_wmax[(size_t)b * HW_ + pixg] = wmax;
    out_wmean[(size_t)b * HW_ + pixg] = 1.f / 48.f;
  }
  __syncthreads();

  // ---- weighted output: re-read feats (L1/L2-hot) * w_max ----
  {
    float* oa = out_assp + (size_t)b * D_ * HW_ + p0;
    float4 w4 = *(const float4*)(wm + tcd * 4);
    #pragma unroll
    for (int it = 0; it < 16; ++it) {
      int d = it * 16 + trd;
      float4 v = *(const float4*)(fb + (size_t)d * HW_ + tcd * 4);
      v.x *= w4.x; v.y *= w4.y; v.z *= w4.z; v.w *= w4.w;
      *(float4*)(oa + (size_t)d * HW_ + tcd * 4) = v;
    }
  }
  __syncthreads();   // main stores drained before replaced-pixel overwrite

  // ---- fix pass: replaced pixels get proto_f32 * wmax ----
  {
    float* oa = out_assp + (size_t)b * D_ * HW_ + p0;
    int cnt = 0;
    for (int pp = 0; pp < PT_; ++pp) {
      int c = map_s[pp];
      if (c < 0) continue;
      if ((cnt & 1) == wid) {
        float w = wm[pp];
        float4 pv = *(const float4*)(protos + ((size_t)b * NC_ + c) * D_ + lane * 4);
        oa[(size_t)(lane * 4 + 0) * HW_ + pp] = pv.x * w;
        oa[(size_t)(lane * 4 + 1) * HW_ + pp] = pv.y * w;
        oa[(size_t)(lane * 4 + 2) * HW_ + pp] = pv.z * w;
        oa[(size_t)(lane * 4 + 3) * HW_ + pp] = pv.w * w;
      }
      ++cnt;
    }
  }
}

extern "C" void kernel_launch(void* const* d_in, const int* in_sizes, int n_in,
                              void* d_out, int out_size, void* d_ws, size_t ws_size,
                              hipStream_t stream) {
  const float* feats  = (const float*)d_in[0];
  const float* protos = (const float*)d_in[1];
  const float* Wk     = (const float*)d_in[2];
  const float* bk     = (const float*)d_in[3];
  const float* Wq     = (const float*)d_in[4];
  const float* bq     = (const float*)d_in[5];
  const int*   xc     = (const int*)d_in[6];
  const int*   yc     = (const int*)d_in[7];
  const int    P      = in_sizes[6];   // 819

  float* out       = (float*)d_out;
  float* out_assp  = out;                                  // B*D*HW
  float* out_po    = out_assp + (size_t)B_ * D_ * HW_;     // 48*B*128
  float* out_wmax  = out_po + (size_t)NC_ * B_ * KO_;      // B*HW
  float* out_sim   = out_wmax + (size_t)B_ * HW_;          // B*48*HW
  float* out_wmean = out_sim + (size_t)B_ * NC_ * HW_;     // B*HW

  unsigned char* ws = (unsigned char*)d_ws;
  unsigned short* wk_bf = (unsigned short*)ws;                   // 65536 B
  unsigned short* q_bf  = (unsigned short*)(ws + 65536);         // 98304 B
  short* map            = (short*)(ws + 65536 + 98304);          // 262144 B

  p1_kernel<<<dim3(NC_, B_), 128, 0, stream>>>(protos, Wq, bq, Wk, wk_bf, q_bf, out_po, map);
  p2_kernel<<<dim3(P, B_), 64, 0, stream>>>(feats, protos, xc, yc, map);
  m_kernel<<<dim3(HW_ / PT_, B_), 128, 0, stream>>>(feats, protos, wk_bf, bk, q_bf, map,
                                                    out_assp, out_wmax, out_sim, out_wmean);
}

// Round 4
// 147.083 us; speedup vs baseline: 1.3202x; 1.3202x over previous
//
#include <hip/hip_runtime.h>

#define B_   8
#define D_   256
#define HW_  16384
#define NC_  48     // NCLS*K
#define KO_  128    // key channels
#define PT_  32     // pixels per tile

using bf16x8 = __attribute__((ext_vector_type(8))) short;
using f32x4  = __attribute__((ext_vector_type(4))) float;
typedef unsigned long long ull;

__device__ __forceinline__ unsigned short f2bf(float f) {
  unsigned int u = __float_as_uint(f);
  u += 0x7FFFu + ((u >> 16) & 1u);   // RNE
  return (unsigned short)(u >> 16);
}
__device__ __forceinline__ float bf2f(unsigned short h) {
  return __uint_as_float(((unsigned)h) << 16);
}
__device__ __forceinline__ ull pack4bf(float4 v) {
  return (ull)f2bf(v.x) | ((ull)f2bf(v.y) << 16)
       | ((ull)f2bf(v.z) << 32) | ((ull)f2bf(v.w) << 48);
}

// ---------------- P1: q = Wq.protos + bq ; M = q.Wk (bf16) ; beta = q.bk ; map init ----------------
__global__ __launch_bounds__(128) void p1_kernel(
    const float* __restrict__ protos, const float* __restrict__ Wq,
    const float* __restrict__ bq, const float* __restrict__ Wk,
    const float* __restrict__ bk,
    unsigned short* __restrict__ m_bf, float* __restrict__ beta,
    float* __restrict__ protos_out, int* __restrict__ map_i) {
  __shared__ float qs[KO_];
  const int c = blockIdx.x;   // 0..47
  const int b = blockIdx.y;   // 0..7
  const int o = threadIdx.x;  // 0..127
  const int i = c >> 3;
  const float* wq = Wq + ((size_t)i * KO_ + o) * D_;
  const float* pp = protos + ((size_t)b * NC_ + c) * D_;
  float acc = bq[i * KO_ + o];
  for (int d = 0; d < D_; d += 4) {
    float4 wv = *(const float4*)(wq + d);
    float4 pv = *(const float4*)(pp + d);
    acc += wv.x * pv.x + wv.y * pv.y + wv.z * pv.z + wv.w * pv.w;
  }
  qs[o] = acc;
  protos_out[((size_t)c * B_ + b) * KO_ + o] = acc;
  const int gid = (b * NC_ + c) * KO_ + o;    // 0..49151
  if (gid < B_ * HW_ / 4) map_i[gid] = -1;    // int8 map, 4 bytes at a time
  __syncthreads();
  // M[c][d] for d = 2o, 2o+1
  float m0 = 0.f, m1 = 0.f;
  for (int oo = 0; oo < KO_; ++oo) {
    float2 wv = *(const float2*)(Wk + (size_t)oo * D_ + o * 2);
    float qv = qs[oo];
    m0 += qv * wv.x;
    m1 += qv * wv.y;
  }
  unsigned pk = (unsigned)f2bf(m0) | ((unsigned)f2bf(m1) << 16);
  *(unsigned*)(m_bf + (size_t)(b * NC_ + c) * D_ + o * 2) = pk;
  // beta = q . bk
  if (o < 64) {
    float p = qs[o] * bk[o] + qs[o + 64] * bk[o + 64];
    for (int off = 32; off; off >>= 1) p += __shfl_down(p, off);
    if (o == 0) beta[b * NC_ + c] = p;
  }
}

// ---------------- P2: nearest prototype per sampled pixel -> map (exact f32) ----------------
__global__ void p2_kernel(const float* __restrict__ feats,
                          const float* __restrict__ protos,
                          const int* __restrict__ xc,
                          const int* __restrict__ yc,
                          signed char* __restrict__ map) {
  const int sp = blockIdx.x;
  const int b  = blockIdx.y;
  const int lane = threadIdx.x;  // 0..63
  __shared__ float sel[D_];
  const int pix = xc[sp] * 128 + yc[sp];
  const float* fb = feats + (size_t)b * D_ * HW_ + pix;
  for (int k = 0; k < 4; ++k) {
    int d = lane + k * 64;
    sel[d] = fb[(size_t)d * HW_];
  }
  __syncthreads();
  float d2 = 3.4e38f;
  int bi = lane;
  if (lane < NC_) {
    const float* pf = protos + ((size_t)b * NC_ + lane) * D_;
    float nrm = 0.f, dot = 0.f;
    for (int d = 0; d < D_; d += 4) {
      float4 pv = *(const float4*)(pf + d);
      float4 sv = *(const float4*)(sel + d);
      nrm += pv.x * pv.x + pv.y * pv.y + pv.z * pv.z + pv.w * pv.w;
      dot += pv.x * sv.x + pv.y * sv.y + pv.z * sv.z + pv.w * sv.w;
    }
    d2 = nrm - 2.f * dot;
  }
  for (int off = 32; off > 0; off >>= 1) {
    float ov = __shfl_down(d2, off);
    int   oi = __shfl_down(bi, off);
    if (ov < d2 || (ov == d2 && oi < bi)) { d2 = ov; bi = oi; }
  }
  if (lane == 0) map[(size_t)b * HW_ + pix] = (signed char)bi;
}

// ---------------- M: fused replace + sim GEMM + softmax + outputs ----------------
// 128 threads (2 waves), 32 pixels/block.
// LDS F tile: bf16 [p][d], 512B rows, byte swizzle X(p) = ((p&7)<<4) ^ ((p>>3)<<3)
// (all accesses 8B, bank-floor on both ds_write_b64 and ds_read_b64).
__global__ __launch_bounds__(128, 4) void m_kernel(
    const float* __restrict__ feats, const float* __restrict__ protos,
    const unsigned short* __restrict__ m_bf, const float* __restrict__ beta,
    const signed char* __restrict__ map,
    float* __restrict__ out_assp, float* __restrict__ out_wmax,
    float* __restrict__ out_sim, float* __restrict__ out_wmean) {
  __shared__ __align__(16) unsigned short Fb[PT_ * 256];   // 16 KB
  __shared__ float wm[PT_];
  __shared__ signed char map_s[PT_];

  const int tid  = threadIdx.x;   // 0..127
  const int lane = tid & 63;
  const int wid  = tid >> 6;      // 0..1
  const int g    = lane >> 4;     // 0..3
  const int lr   = lane & 15;
  const int b    = blockIdx.y;
  const int p0   = blockIdx.x * PT_;

  if (tid < PT_) map_s[tid] = map[(size_t)b * HW_ + p0 + tid];
  __syncthreads();

  unsigned char* fbB = (unsigned char*)Fb;
  const int ps = tid & 31;        // staging: this thread's pixel column
  const int dq = tid >> 5;        // 0..3  (d-quad group)
  const unsigned Xs = (unsigned)(((ps & 7) << 4) ^ ((ps >> 3) << 3));

  // ---- stage F tile (with prototype substitution), f32 -> bf16 ----
  {
    const int c = map_s[ps];
    const float* fcol = feats + (size_t)b * D_ * HW_ + p0 + ps;
    const float* prow = protos + ((size_t)b * NC_ + (c >= 0 ? c : 0)) * D_;
    #pragma unroll
    for (int it = 0; it < 16; ++it) {
      const int d0 = it * 16 + dq * 4;
      float4 v;
      if (c >= 0) {
        v = *(const float4*)(prow + d0);
      } else {
        v.x = fcol[(size_t)(d0 + 0) * HW_];
        v.y = fcol[(size_t)(d0 + 1) * HW_];
        v.z = fcol[(size_t)(d0 + 2) * HW_];
        v.w = fcol[(size_t)(d0 + 3) * HW_];
      }
      *(ull*)(fbB + ps * 512 + ((unsigned)(d0 * 2) ^ Xs)) = pack4bf(v);
    }
  }
  __syncthreads();

  // ---- sim GEMM: sim[c][p] = M(48x256) x F(256x32) + beta ----
  const int p = wid * 16 + lr;
  const unsigned Xp = (unsigned)(((p & 7) << 4) ^ ((p >> 3) << 3));
  f32x4 sacc[3] = {};
  {
    const unsigned short* mrow = m_bf + (size_t)b * NC_ * D_;
    #pragma unroll
    for (int ks = 0; ks < 8; ++ks) {
      const unsigned base = (unsigned)(ks * 64 + g * 16);  // byte offs of d=ks*32+g*8
      ull lo = *(const ull*)(fbB + p * 512 + (base ^ Xp));
      ull hi = *(const ull*)(fbB + p * 512 + ((base + 8) ^ Xp));
      union { ull u[2]; bf16x8 v8; } bu;
      bu.u[0] = lo; bu.u[1] = hi;
      const unsigned short* ar = mrow + ks * 32 + g * 8;
      #pragma unroll
      for (int ct = 0; ct < 3; ++ct) {
        bf16x8 af = *(const bf16x8*)(ar + (size_t)(ct * 16 + lr) * D_);
        sacc[ct] = __builtin_amdgcn_mfma_f32_16x16x32_bf16(af, bu.v8, sacc[ct], 0, 0, 0);
      }
    }
  }

  // ---- + beta, softmax over c (4 lanes share a pixel: xor 16, 32) ----
  #pragma unroll
  for (int ct = 0; ct < 3; ++ct) {
    float4 bt = *(const float4*)(beta + b * NC_ + ct * 16 + g * 4);
    sacc[ct][0] += bt.x; sacc[ct][1] += bt.y;
    sacc[ct][2] += bt.z; sacc[ct][3] += bt.w;
  }
  float m = -3.4e38f;
  #pragma unroll
  for (int ct = 0; ct < 3; ++ct)
    #pragma unroll
    for (int r = 0; r < 4; ++r) m = fmaxf(m, sacc[ct][r]);
  m = fmaxf(m, __shfl_xor(m, 16));
  m = fmaxf(m, __shfl_xor(m, 32));
  const float sc = 1.0f / 6.0f;   // K/C = 8/48
  float s = 0.f;
  #pragma unroll
  for (int ct = 0; ct < 3; ++ct)
    #pragma unroll
    for (int r = 0; r < 4; ++r) s += __expf((sacc[ct][r] - m) * sc);
  s += __shfl_xor(s, 16);
  s += __shfl_xor(s, 32);
  const float wmax = 1.f / s;

  // ---- write sim ----
  const size_t pixg = (size_t)p0 + p;
  #pragma unroll
  for (int ct = 0; ct < 3; ++ct)
    #pragma unroll
    for (int r = 0; r < 4; ++r) {
      int c = ct * 16 + g * 4 + r;
      out_sim[((size_t)b * NC_ + c) * HW_ + pixg] = sacc[ct][r];
    }
  if (g == 0) {
    wm[p] = wmax;
    out_wmax[(size_t)b * HW_ + pixg] = wmax;
    out_wmean[(size_t)b * HW_ + pixg] = 1.f / 48.f;
  }
  __syncthreads();

  // ---- weighted output from LDS: out[d][ps] = bf2f(F[ps][d]) * wm[ps] ----
  {
    const float w = wm[ps];
    float* oa = out_assp + (size_t)b * D_ * HW_ + p0 + ps;
    #pragma unroll
    for (int it = 0; it < 16; ++it) {
      const int d0 = it * 16 + dq * 4;
      ull r = *(const ull*)(fbB + ps * 512 + ((unsigned)(d0 * 2) ^ Xs));
      oa[(size_t)(d0 + 0) * HW_] = bf2f((unsigned short)(r      )) * w;
      oa[(size_t)(d0 + 1) * HW_] = bf2f((unsigned short)(r >> 16)) * w;
      oa[(size_t)(d0 + 2) * HW_] = bf2f((unsigned short)(r >> 32)) * w;
      oa[(size_t)(d0 + 3) * HW_] = bf2f((unsigned short)(r >> 48)) * w;
    }
  }
}

extern "C" void kernel_launch(void* const* d_in, const int* in_sizes, int n_in,
                              void* d_out, int out_size, void* d_ws, size_t ws_size,
                              hipStream_t stream) {
  const float* feats  = (const float*)d_in[0];
  const float* protos = (const float*)d_in[1];
  const float* Wk     = (const float*)d_in[2];
  const float* bk     = (const float*)d_in[3];
  const float* Wq     = (const float*)d_in[4];
  const float* bq     = (const float*)d_in[5];
  const int*   xc     = (const int*)d_in[6];
  const int*   yc     = (const int*)d_in[7];
  const int    P      = in_sizes[6];   // 819

  float* out       = (float*)d_out;
  float* out_assp  = out;                                  // B*D*HW
  float* out_po    = out_assp + (size_t)B_ * D_ * HW_;     // 48*B*128
  float* out_wmax  = out_po + (size_t)NC_ * B_ * KO_;      // B*HW
  float* out_sim   = out_wmax + (size_t)B_ * HW_;          // B*48*HW
  float* out_wmean = out_sim + (size_t)B_ * NC_ * HW_;     // B*HW

  unsigned char* ws = (unsigned char*)d_ws;
  unsigned short* m_bf = (unsigned short*)ws;                    // 196608 B
  float* beta          = (float*)(ws + 196608);                  // 1536 B (pad to 198144)
  signed char* map     = (signed char*)(ws + 198144);            // 131072 B

  p1_kernel<<<dim3(NC_, B_), 128, 0, stream>>>(protos, Wq, bq, Wk, bk,
                                               m_bf, beta, out_po, (int*)map);
  p2_kernel<<<dim3(P, B_), 64, 0, stream>>>(feats, protos, xc, yc, map);
  m_kernel<<<dim3(HW_ / PT_, B_), 128, 0, stream>>>(feats, protos, m_bf, beta, map,
                                                    out_assp, out_wmax, out_sim, out_wmean);
}

// Round 5
// 132.312 us; speedup vs baseline: 1.4675x; 1.1116x over previous
//
#include <hip/hip_runtime.h>

#define B_   8
#define D_   256
#define HW_  16384
#define NC_  48     // NCLS*K
#define KO_  128    // key channels
#define PT_  32     // pixels per tile

using bf16x8 = __attribute__((ext_vector_type(8))) short;
using f32x4  = __attribute__((ext_vector_type(4))) float;
typedef unsigned long long ull;

__device__ __forceinline__ unsigned short f2bf(float f) {
  unsigned int u = __float_as_uint(f);
  u += 0x7FFFu + ((u >> 16) & 1u);   // RNE
  return (unsigned short)(u >> 16);
}
__device__ __forceinline__ ull pack4bf(float a, float b, float c, float d) {
  return (ull)f2bf(a) | ((ull)f2bf(b) << 16)
       | ((ull)f2bf(c) << 32) | ((ull)f2bf(d) << 48);
}

// ---------------- P1: q = Wq.protos + bq ; M = q.Wk packed to MFMA frag order ;
//                      beta = q.bk ; map init ----------------
// m_pk layout: bf16x8 frag index = (b*24 + ks*3 + ct)*64 + lane, lane = g*16+lr,
// frag[i] = M[ct*16+lr][ks*32+g*8+i]
__global__ __launch_bounds__(128) void p1_kernel(
    const float* __restrict__ protos, const float* __restrict__ Wq,
    const float* __restrict__ bq, const float* __restrict__ Wk,
    const float* __restrict__ bk,
    unsigned short* __restrict__ m_pk, float* __restrict__ beta,
    float* __restrict__ protos_out, int* __restrict__ map_i) {
  __shared__ float qs[KO_];
  const int c = blockIdx.x;   // 0..47
  const int b = blockIdx.y;   // 0..7
  const int o = threadIdx.x;  // 0..127
  const int i = c >> 3;
  const float* wq = Wq + ((size_t)i * KO_ + o) * D_;
  const float* pp = protos + ((size_t)b * NC_ + c) * D_;
  float acc = bq[i * KO_ + o];
  for (int d = 0; d < D_; d += 4) {
    float4 wv = *(const float4*)(wq + d);
    float4 pv = *(const float4*)(pp + d);
    acc += wv.x * pv.x + wv.y * pv.y + wv.z * pv.z + wv.w * pv.w;
  }
  qs[o] = acc;
  protos_out[((size_t)c * B_ + b) * KO_ + o] = acc;
  const int gid = (b * NC_ + c) * KO_ + o;    // 0..49151
  if (gid < B_ * HW_ / 4) map_i[gid] = -1;    // int8 map, 4 bytes at a time
  __syncthreads();
  // M[c][d] for d = 2o, 2o+1
  float m0 = 0.f, m1 = 0.f;
  for (int oo = 0; oo < KO_; ++oo) {
    float2 wv = *(const float2*)(Wk + (size_t)oo * D_ + o * 2);
    float qv = qs[oo];
    m0 += qv * wv.x;
    m1 += qv * wv.y;
  }
  // repack: d=2o -> ks=o>>4, g=(o>>2)&3, i=(o&3)*2 ; ct=c>>4, lr=c&15
  {
    const int ks = o >> 4, g = (o >> 2) & 3, ii = (o & 3) * 2;
    const int ct = c >> 4, lr = c & 15;
    const size_t fidx = ((size_t)(b * 24 + ks * 3 + ct) * 64 + g * 16 + lr) * 8 + ii;
    unsigned pk = (unsigned)f2bf(m0) | ((unsigned)f2bf(m1) << 16);
    *(unsigned*)(m_pk + fidx) = pk;
  }
  // beta = q . bk
  if (o < 64) {
    float p = qs[o] * bk[o] + qs[o + 64] * bk[o + 64];
    for (int off = 32; off; off >>= 1) p += __shfl_down(p, off);
    if (o == 0) beta[b * NC_ + c] = p;
  }
}

// ---------------- P2: nearest prototype per sampled pixel -> map (exact f32) ----------------
__global__ void p2_kernel(const float* __restrict__ feats,
                          const float* __restrict__ protos,
                          const int* __restrict__ xc,
                          const int* __restrict__ yc,
                          signed char* __restrict__ map) {
  const int sp = blockIdx.x;
  const int b  = blockIdx.y;
  const int lane = threadIdx.x;  // 0..63
  __shared__ float sel[D_];
  const int pix = xc[sp] * 128 + yc[sp];
  const float* fb = feats + (size_t)b * D_ * HW_ + pix;
  for (int k = 0; k < 4; ++k) {
    int d = lane + k * 64;
    sel[d] = fb[(size_t)d * HW_];
  }
  __syncthreads();
  float d2 = 3.4e38f;
  int bi = lane;
  if (lane < NC_) {
    const float* pf = protos + ((size_t)b * NC_ + lane) * D_;
    float nrm = 0.f, dot = 0.f;
    for (int d = 0; d < D_; d += 4) {
      float4 pv = *(const float4*)(pf + d);
      float4 sv = *(const float4*)(sel + d);
      nrm += pv.x * pv.x + pv.y * pv.y + pv.z * pv.z + pv.w * pv.w;
      dot += pv.x * sv.x + pv.y * sv.y + pv.z * sv.z + pv.w * sv.w;
    }
    d2 = nrm - 2.f * dot;
  }
  for (int off = 32; off > 0; off >>= 1) {
    float ov = __shfl_down(d2, off);
    int   oi = __shfl_down(bi, off);
    if (ov < d2 || (ov == d2 && oi < bi)) { d2 = ov; bi = oi; }
  }
  if (lane == 0) map[(size_t)b * HW_ + pix] = (signed char)bi;
}

// ---------------- M: fused replace + sim GEMM + softmax + outputs ----------------
// 128 threads (2 waves), 32 pixels/block.
// LDS F tile: bf16 [p][d], 512B rows, byte swizzle X(p) = ((p&7)<<4) ^ ((p>>3)<<3).
// Staging: thread owns 4d x 4p f32 subtiles (dwordx4 loads), keeps f32 in regs for output.
__global__ __launch_bounds__(128, 2) void m_kernel(
    const float* __restrict__ feats, const float* __restrict__ protos,
    const unsigned short* __restrict__ m_pk, const float* __restrict__ beta,
    const signed char* __restrict__ map,
    float* __restrict__ out_assp, float* __restrict__ out_wmax,
    float* __restrict__ out_sim, float* __restrict__ out_wmean) {
  __shared__ __align__(16) unsigned short Fb[PT_ * 256];   // 16 KB
  __shared__ __align__(16) float simb[NC_ * PT_];          // 6 KB
  __shared__ float wm[PT_];
  __shared__ signed char map_s[PT_];

  const int tid  = threadIdx.x;   // 0..127
  const int lane = tid & 63;
  const int wid  = tid >> 6;      // 0..1
  const int g    = lane >> 4;     // 0..3
  const int lr   = lane & 15;
  const int b    = blockIdx.y;
  const int p0   = blockIdx.x * PT_;

  if (tid < PT_) map_s[tid] = map[(size_t)b * HW_ + p0 + tid];
  __syncthreads();

  unsigned char* fbB = (unsigned char*)Fb;
  const int x  = tid & 7;     // pixel quad: pixels x*4..x*4+3
  const int dr = tid >> 3;    // 0..15

  // ---- stage F tile: 16 dwordx4 loads, in-reg substitute+transpose, 16 ds_write_b64 ----
  float V[64];   // V[it*16 + k*4 + j] = F[d = it*64+dr*4+k][pixel x*4+j], fully static idx
  {
    const float* fb = feats + (size_t)b * D_ * HW_ + p0 + x * 4;
    const float* prb = protos + (size_t)b * NC_ * D_;
    int cj[4];
    #pragma unroll
    for (int j = 0; j < 4; ++j) cj[j] = map_s[x * 4 + j];
    #pragma unroll
    for (int it = 0; it < 4; ++it) {
      const int d0 = it * 64 + dr * 4;
      #pragma unroll
      for (int k = 0; k < 4; ++k) {
        float4 t = *(const float4*)(fb + (size_t)(d0 + k) * HW_);
        V[it*16 + k*4 + 0] = t.x; V[it*16 + k*4 + 1] = t.y;
        V[it*16 + k*4 + 2] = t.z; V[it*16 + k*4 + 3] = t.w;
      }
      #pragma unroll
      for (int j = 0; j < 4; ++j) {
        if (cj[j] >= 0) {
          float4 pv = *(const float4*)(prb + (size_t)cj[j] * D_ + d0);
          V[it*16 + 0*4 + j] = pv.x; V[it*16 + 1*4 + j] = pv.y;
          V[it*16 + 2*4 + j] = pv.z; V[it*16 + 3*4 + j] = pv.w;
        }
      }
      #pragma unroll
      for (int j = 0; j < 4; ++j) {
        const int p = x * 4 + j;
        const unsigned X = (unsigned)(((p & 7) << 4) ^ ((p >> 3) << 3));
        *(ull*)(fbB + p * 512 + ((unsigned)(d0 * 2) ^ X)) =
            pack4bf(V[it*16 + 0*4 + j], V[it*16 + 1*4 + j],
                    V[it*16 + 2*4 + j], V[it*16 + 3*4 + j]);
      }
    }
  }
  __syncthreads();

  // ---- sim GEMM: sim[c][p] = M(48x256) x F(256x32) + beta ----
  const int p = wid * 16 + lr;
  const unsigned Xp = (unsigned)(((p & 7) << 4) ^ ((p >> 3) << 3));
  f32x4 sacc[3] = {};
  {
    const unsigned short* apk = m_pk + (size_t)b * 24 * 64 * 8 + lane * 8;
    #pragma unroll
    for (int ks = 0; ks < 8; ++ks) {
      const unsigned base = (unsigned)(ks * 64 + g * 16);
      ull lo = *(const ull*)(fbB + p * 512 + (base ^ Xp));
      ull hi = *(const ull*)(fbB + p * 512 + ((base + 8) ^ Xp));
      union { ull u[2]; bf16x8 v8; } bu;
      bu.u[0] = lo; bu.u[1] = hi;
      #pragma unroll
      for (int ct = 0; ct < 3; ++ct) {
        bf16x8 af = *(const bf16x8*)(apk + (size_t)(ks * 3 + ct) * 64 * 8);
        sacc[ct] = __builtin_amdgcn_mfma_f32_16x16x32_bf16(af, bu.v8, sacc[ct], 0, 0, 0);
      }
    }
  }

  // ---- + beta, softmax over c (4 lanes share a pixel: xor 16, 32) ----
  #pragma unroll
  for (int ct = 0; ct < 3; ++ct) {
    float4 bt = *(const float4*)(beta + b * NC_ + ct * 16 + g * 4);
    sacc[ct][0] += bt.x; sacc[ct][1] += bt.y;
    sacc[ct][2] += bt.z; sacc[ct][3] += bt.w;
  }
  float m = -3.4e38f;
  #pragma unroll
  for (int ct = 0; ct < 3; ++ct)
    #pragma unroll
    for (int r = 0; r < 4; ++r) m = fmaxf(m, sacc[ct][r]);
  m = fmaxf(m, __shfl_xor(m, 16));
  m = fmaxf(m, __shfl_xor(m, 32));
  const float sc = 1.0f / 6.0f;   // K/C = 8/48
  float s = 0.f;
  #pragma unroll
  for (int ct = 0; ct < 3; ++ct)
    #pragma unroll
    for (int r = 0; r < 4; ++r) s += __expf((sacc[ct][r] - m) * sc);
  s += __shfl_xor(s, 16);
  s += __shfl_xor(s, 32);
  const float wmax = 1.f / s;

  // ---- sacc -> simb LDS ; wmax bookkeeping ----
  #pragma unroll
  for (int ct = 0; ct < 3; ++ct)
    #pragma unroll
    for (int r = 0; r < 4; ++r)
      simb[(ct * 16 + g * 4 + r) * PT_ + p] = sacc[ct][r];
  const size_t pixg = (size_t)p0 + p;
  if (g == 0) {
    wm[p] = wmax;
    out_wmax[(size_t)b * HW_ + pixg] = wmax;
    out_wmean[(size_t)b * HW_ + pixg] = 1.f / 48.f;
  }
  __syncthreads();

  // ---- sim stores: vectorized float4 across pixels ----
  #pragma unroll
  for (int r3 = 0; r3 < 3; ++r3) {
    const int f  = r3 * 128 + tid;   // 0..383
    const int c  = f >> 3;
    const int po = (f & 7) * 4;
    float4 sv = *(const float4*)(simb + c * PT_ + po);
    *(float4*)(out_sim + ((size_t)b * NC_ + c) * HW_ + p0 + po) = sv;
  }

  // ---- weighted output from registers: out[d][p] = V * wm[p] (f32 exact) ----
  {
    float4 w4 = *(const float4*)(wm + x * 4);
    float* oa = out_assp + (size_t)b * D_ * HW_ + p0 + x * 4;
    #pragma unroll
    for (int it = 0; it < 4; ++it) {
      const int d0 = it * 64 + dr * 4;
      #pragma unroll
      for (int k = 0; k < 4; ++k) {
        float4 o;
        o.x = V[it*16 + k*4 + 0] * w4.x;
        o.y = V[it*16 + k*4 + 1] * w4.y;
        o.z = V[it*16 + k*4 + 2] * w4.z;
        o.w = V[it*16 + k*4 + 3] * w4.w;
        *(float4*)(oa + (size_t)(d0 + k) * HW_) = o;
      }
    }
  }
}

extern "C" void kernel_launch(void* const* d_in, const int* in_sizes, int n_in,
                              void* d_out, int out_size, void* d_ws, size_t ws_size,
                              hipStream_t stream) {
  const float* feats  = (const float*)d_in[0];
  const float* protos = (const float*)d_in[1];
  const float* Wk     = (const float*)d_in[2];
  const float* bk     = (const float*)d_in[3];
  const float* Wq     = (const float*)d_in[4];
  const float* bq     = (const float*)d_in[5];
  const int*   xc     = (const int*)d_in[6];
  const int*   yc     = (const int*)d_in[7];
  const int    P      = in_sizes[6];   // 819

  float* out       = (float*)d_out;
  float* out_assp  = out;                                  // B*D*HW
  float* out_po    = out_assp + (size_t)B_ * D_ * HW_;     // 48*B*128
  float* out_wmax  = out_po + (size_t)NC_ * B_ * KO_;      // B*HW
  float* out_sim   = out_wmax + (size_t)B_ * HW_;          // B*48*HW
  float* out_wmean = out_sim + (size_t)B_ * NC_ * HW_;     // B*HW

  unsigned char* ws = (unsigned char*)d_ws;
  unsigned short* m_pk = (unsigned short*)ws;                    // 196608 B
  float* beta          = (float*)(ws + 196608);                  // 1536 B (pad to 198144)
  signed char* map     = (signed char*)(ws + 198144);            // 131072 B

  p1_kernel<<<dim3(NC_, B_), 128, 0, stream>>>(protos, Wq, bq, Wk, bk,
                                               m_pk, beta, out_po, (int*)map);
  p2_kernel<<<dim3(P, B_), 64, 0, stream>>>(feats, protos, xc, yc, map);
  m_kernel<<<dim3(HW_ / PT_, B_), 128, 0, stream>>>(feats, protos, m_pk, beta, map,
                                                    out_assp, out_wmax, out_sim, out_wmean);
}